// Round 9
// baseline (159.258 us; speedup 1.0000x reference)
//
#include <hip/hip_runtime.h>
#include <math.h>

// ---------------- workspace layout (float offsets) ----------------
// Only the first 16 tokens per batch matter (E = HEAD = 16 slices the T axis).
#define WS_XN    0          // 64*1024                  LN'd x rows
#define WS_QKVP  65536      // 8 * 64*3072              split-K partials of q|k|v
#define WS_DIFF  1638400    // 1                        sum |ai1-ai0|
#define WS_AI1   1638404    // 64*1024                  iter-1 attention out
#define WS_AI2   1703940    // 64*1024                  iter-2 attention out
#define WS_WT    1769476    // 3 * 4096                 WlqT|WlkT|WlvT  ([k][d] layout)
// end: 1781764 floats = ~7.1 MB

__device__ __forceinline__ float4 f4zero() { return make_float4(0.f, 0.f, 0.f, 0.f); }
__device__ __forceinline__ float4 f4add(float4 a, float4 b) {
    return make_float4(a.x + b.x, a.y + b.y, a.z + b.z, a.w + b.w);
}
__device__ __forceinline__ float4 f4fma(float s, float4 a, float4 c) {
    return make_float4(fmaf(s, a.x, c.x), fmaf(s, a.y, c.y),
                       fmaf(s, a.z, c.z), fmaf(s, a.w, c.w));
}
__device__ __forceinline__ float dot4acc(float4 a, float4 b, float acc) {
    acc = fmaf(a.x, b.x, acc); acc = fmaf(a.y, b.y, acc);
    acc = fmaf(a.z, b.z, acc); acc = fmaf(a.w, b.w, acc);
    return acc;
}

// 16x64 @ 64x64 GEMM, both operands in LDS. A: [k][t] stride 20 (broadcast
// reads). W: [k][d] stride 64 (16 distinct float4/wave -> 2-way banks, free).
__device__ __forceinline__ void gemm_lds(const float* __restrict__ ldsA, int tq,
                                         const float* __restrict__ ldsW, int dq,
                                         float acc[4][4]) {
#pragma unroll 8
    for (int k = 0; k < 64; ++k) {
        float4 a4 = *(const float4*)&ldsA[k * 20 + 4 * tq];
        float4 b4 = *(const float4*)&ldsW[k * 64 + 4 * dq];
        float av[4] = { a4.x, a4.y, a4.z, a4.w };
#pragma unroll
        for (int i = 0; i < 4; i++) {
            acc[i][0] = fmaf(av[i], b4.x, acc[i][0]);
            acc[i][1] = fmaf(av[i], b4.y, acc[i][1]);
            acc[i][2] = fmaf(av[i], b4.z, acc[i][2]);
            acc[i][3] = fmaf(av[i], b4.w, acc[i][3]);
        }
    }
}

// ---------------- K1: LayerNorm of 64 rows + weight transpose ----------------
__global__ __launch_bounds__(256) void k_ln(const float* __restrict__ x,
                                            const float* __restrict__ lna,
                                            const float* __restrict__ Wlq,
                                            const float* __restrict__ Wlk,
                                            const float* __restrict__ Wlv,
                                            float* __restrict__ xn,
                                            float* __restrict__ wt,
                                            float* __restrict__ diffg) {
    if (blockIdx.x >= 64) {
        int m = blockIdx.x - 64;
        const float* W = (m == 0) ? Wlq : (m == 1) ? Wlk : Wlv;
        float* dst = wt + m * 4096;
        for (int i = threadIdx.x; i < 4096; i += 256) {
            int k = i >> 6, d = i & 63;
            dst[i] = W[d * 64 + k];
        }
        return;
    }
    int r = blockIdx.x;                 // 0..63 = b*16 + t
    int b = r >> 4, t = r & 15;
    if (blockIdx.x == 0 && threadIdx.x == 0) diffg[0] = 0.f;
    const float* row = x + (size_t)(b * 2048 + t) * 1024;
    int tid = threadIdx.x;
    float4 xv = *(const float4*)&row[tid * 4];
    float s1 = xv.x + xv.y + xv.z + xv.w;
    float s2 = xv.x * xv.x + xv.y * xv.y + xv.z * xv.z + xv.w * xv.w;
    for (int off = 32; off; off >>= 1) {
        s1 += __shfl_xor(s1, off);
        s2 += __shfl_xor(s2, off);
    }
    __shared__ float ssum[4], ssq[4];
    int wv = tid >> 6, lane = tid & 63;
    if (lane == 0) { ssum[wv] = s1; ssq[wv] = s2; }
    __syncthreads();
    float tot = ssum[0] + ssum[1] + ssum[2] + ssum[3];
    float tq  = ssq[0] + ssq[1] + ssq[2] + ssq[3];
    float m   = tot * (1.0f / 1024.0f);
    float var = tq * (1.0f / 1024.0f) - m * m;
    float rs  = rsqrtf(var + 1e-5f);
    float4 w4 = *(const float4*)&lna[tid * 4];
    float4 o  = make_float4((xv.x - m) * rs * w4.x, (xv.y - m) * rs * w4.y,
                            (xv.z - m) * rs * w4.z, (xv.w - m) * rs * w4.w);
    *(float4*)&xn[r * 1024 + tid * 4] = o;
}

// ---------------- K2: q|k|v = xn @ [Wq|Wk|Wv]^T, split-K partials ----------------
__global__ __launch_bounds__(256) void k_qkv(const float* __restrict__ xn,
                                             const float* __restrict__ Wq,
                                             const float* __restrict__ Wk,
                                             const float* __restrict__ Wv,
                                             float* __restrict__ qkvp) {
    int ct  = blockIdx.x;               // 0..95
    int ksl = blockIdx.y;               // 0..7
    int m   = ct >> 5;
    const float* W = (m == 0) ? Wq : (m == 1) ? Wk : Wv;
    int j0 = (ct & 31) * 32;
    int k0 = ksl * 128;
    __shared__ float At[64][132];
    __shared__ float Bt[32][132];
    int tid = threadIdx.x;
    for (int i = tid; i < 2048; i += 256) {
        int r = i >> 5, kk = (i & 31) << 2;
        *(float4*)&At[r][kk] = *(const float4*)&xn[r * 1024 + k0 + kk];
    }
    for (int i = tid; i < 1024; i += 256) {
        int r = i >> 5, kk = (i & 31) << 2;
        *(float4*)&Bt[r][kk] = *(const float4*)&W[(size_t)(j0 + r) * 1024 + k0 + kk];
    }
    __syncthreads();
    int rg = tid >> 4, cg = tid & 15;
    float acc[4][2];
#pragma unroll
    for (int i = 0; i < 4; i++) { acc[i][0] = 0.f; acc[i][1] = 0.f; }
    for (int k = 0; k < 128; k += 4) {
        float4 b0 = *(float4*)&Bt[cg * 2 + 0][k];
        float4 b1 = *(float4*)&Bt[cg * 2 + 1][k];
#pragma unroll
        for (int i = 0; i < 4; i++) {
            float4 a = *(float4*)&At[rg * 4 + i][k];
            acc[i][0] = dot4acc(a, b0, acc[i][0]);
            acc[i][1] = dot4acc(a, b1, acc[i][1]);
        }
    }
    float* dst = qkvp + (size_t)ksl * 196608;
    int colg = ct * 32 + cg * 2;
#pragma unroll
    for (int i = 0; i < 4; i++) {
        *(float2*)&dst[(rg * 4 + i) * 3072 + colg] = make_float2(acc[i][0], acc[i][1]);
    }
}

// ---------------- K3: fold + 3-iteration loop + overlapped bo-broadcast ------
// Blocks 0..63: one per (b,h), weights in LDS (48 KB), fused split-K fold.
// Blocks 64..8255: bo-broadcast writes for ALL 8192 output rows (real rows
// included -- k_wo atomic-adds the Wo partials on top afterwards). These
// no-LDS blocks overlap the compute blocks' ~10 us on the other CUs.
__global__ __launch_bounds__(256, 2) void k_iter(
        const float* __restrict__ qkvp, const float* __restrict__ wt,
        const float* __restrict__ bq,  const float* __restrict__ bv,
        const float* __restrict__ lnc, const float* __restrict__ lnd,
        const float* __restrict__ blq, const float* __restrict__ blk_,
        const float* __restrict__ blv, const float* __restrict__ temp,
        const float* __restrict__ bo,  float* __restrict__ out,
        float* __restrict__ ai1g, float* __restrict__ ai2g,
        float* __restrict__ diffg) {
    __shared__ __align__(16) float wS[12288];      // WlqT|WlkT|WlvT ([k][d])
    __shared__ __align__(16) float qcT[64 * 20];   // [d-or-k][t] stride 20
    __shared__ __align__(16) float kcT[64 * 20];
    __shared__ __align__(16) float vcT[64 * 20];
    __shared__ __align__(16) float qsR[16 * 68];   // row-major [t][d]
    __shared__ __align__(16) float ksR[16 * 68];
    __shared__ __align__(16) float vlR[16 * 68];
    __shared__ float dred[4];

    int tid  = threadIdx.x;

    if (blockIdx.x >= 64) {              // ---- bo-broadcast blocks (all rows)
        int i2 = blockIdx.x - 64;        // 0..8191 = b*2048 + t
        float4 o = *(const float4*)&bo[tid * 4];
        *(float4*)&out[(size_t)i2 * 1024 + tid * 4] = o;
        return;
    }

    int b    = blockIdx.x >> 4, h = blockIdx.x & 15;
    int wv   = tid >> 6, lane = tid & 63;
    float tempv = temp[0];

    int tq = lane >> 4, dq = lane & 15;     // P1 tile coords
    int t2 = tid >> 4,  u  = tid & 15;      // P2 coords
    int rowi2 = b * 16 + t2, col2 = h * 64 + u * 4;

    // ---- weight staging: 12 float4 per thread, independent, pipelined
#pragma unroll
    for (int j = 0; j < 12; ++j) {
        int idx = (tid + j * 256) * 4;
        *(float4*)&wS[idx] = *(const float4*)&wt[idx];
    }

    // ---- fused split-K fold + scale/bias + transposed state staging
    float4 qreg;                                    // qcur[t2][4u..] in register
    {
        const float SCALE = 0.35355339059327378f;   // 64^-0.25
        const float* P = qkvp + rowi2 * 3072 + col2;
        float4 q4 = f4zero(), k4 = f4zero(), v4 = f4zero();
#pragma unroll
        for (int sl = 0; sl < 8; sl++) {
            const float* Ps = P + (size_t)sl * 196608;
            q4 = f4add(q4, *(const float4*)&Ps[0]);
            k4 = f4add(k4, *(const float4*)&Ps[1024]);
            v4 = f4add(v4, *(const float4*)&Ps[2048]);
        }
        float4 bq4 = *(const float4*)&bq[col2];
        float4 bv4 = *(const float4*)&bv[col2];
        qreg = make_float4((q4.x + bq4.x) * SCALE, (q4.y + bq4.y) * SCALE,
                           (q4.z + bq4.z) * SCALE, (q4.w + bq4.w) * SCALE);
        float kv[4] = { k4.x * SCALE, k4.y * SCALE, k4.z * SCALE, k4.w * SCALE };
        float vv[4] = { v4.x + bv4.x, v4.y + bv4.y, v4.z + bv4.z, v4.w + bv4.w };
        float qv[4] = { qreg.x, qreg.y, qreg.z, qreg.w };
#pragma unroll
        for (int c = 0; c < 4; c++) {
            qcT[(u * 4 + c) * 20 + t2] = qv[c];
            kcT[(u * 4 + c) * 20 + t2] = kv[c];
            vcT[(u * 4 + c) * 20 + t2] = vv[c];
        }
    }
    __syncthreads();

    float4 ai0 = f4zero();
    float  dlocal = 0.f;

#pragma unroll 1
    for (int it = 0; it < 3; ++it) {
        float t_it = tempv + 0.005f * (float)it;
        float tsc  = (t_it != 1.0f && t_it > 0.0f) ? rsqrtf(t_it) : 1.0f;

        // ---------------- P1: three GEMMs, wave-specialized ----------------
        if (wv == 0) {
            float acc[4][4];
#pragma unroll
            for (int i = 0; i < 4; i++)
#pragma unroll
                for (int j = 0; j < 4; j++) acc[i][j] = 0.f;
            gemm_lds(qcT, tq, wS, dq, acc);
            float4 bb = *(const float4*)&blq[4 * dq];
            float4 lw = *(const float4*)&lnc[4 * dq];
#pragma unroll
            for (int i = 0; i < 4; i++) {
                acc[i][0] += bb.x; acc[i][1] += bb.y;
                acc[i][2] += bb.z; acc[i][3] += bb.w;
                float s1 = acc[i][0] + acc[i][1] + acc[i][2] + acc[i][3];
                float s2 = acc[i][0]*acc[i][0] + acc[i][1]*acc[i][1]
                         + acc[i][2]*acc[i][2] + acc[i][3]*acc[i][3];
                for (int off = 8; off; off >>= 1) {
                    s1 += __shfl_xor(s1, off); s2 += __shfl_xor(s2, off);
                }
                float m  = s1 * (1.0f / 64.0f);
                float vr = s2 * (1.0f / 64.0f) - m * m;
                float rs = rsqrtf(vr + 1e-5f) * tsc;
                float4 o = make_float4((acc[i][0] - m) * rs * lw.x,
                                       (acc[i][1] - m) * rs * lw.y,
                                       (acc[i][2] - m) * rs * lw.z,
                                       (acc[i][3] - m) * rs * lw.w);
                *(float4*)&qsR[(4 * tq + i) * 68 + 4 * dq] = o;
            }
        } else if (wv == 1) {
            float acc[4][4];
#pragma unroll
            for (int i = 0; i < 4; i++)
#pragma unroll
                for (int j = 0; j < 4; j++) acc[i][j] = 0.f;
            gemm_lds(kcT, tq, wS + 4096, dq, acc);
            float4 bb = *(const float4*)&blk_[4 * dq];
#pragma unroll
            for (int i = 0; i < 4; i++) {
                acc[i][0] += bb.x; acc[i][1] += bb.y;
                acc[i][2] += bb.z; acc[i][3] += bb.w;
            }
            if (it < 2) {                       // kcur_next dead after last iter
#pragma unroll
                for (int j = 0; j < 4; j++) {
                    float4 cv = make_float4(acc[0][j], acc[1][j], acc[2][j], acc[3][j]);
                    *(float4*)&kcT[(4 * dq + j) * 20 + 4 * tq] = cv;
                }
            }
            float4 lw = *(const float4*)&lnd[4 * dq];
#pragma unroll
            for (int i = 0; i < 4; i++) {
                float s1 = acc[i][0] + acc[i][1] + acc[i][2] + acc[i][3];
                float s2 = acc[i][0]*acc[i][0] + acc[i][1]*acc[i][1]
                         + acc[i][2]*acc[i][2] + acc[i][3]*acc[i][3];
                for (int off = 8; off; off >>= 1) {
                    s1 += __shfl_xor(s1, off); s2 += __shfl_xor(s2, off);
                }
                float m  = s1 * (1.0f / 64.0f);
                float vr = s2 * (1.0f / 64.0f) - m * m;
                float rs = rsqrtf(vr + 1e-5f);
                float4 o = make_float4((acc[i][0] - m) * rs * lw.x,
                                       (acc[i][1] - m) * rs * lw.y,
                                       (acc[i][2] - m) * rs * lw.z,
                                       (acc[i][3] - m) * rs * lw.w);
                *(float4*)&ksR[(4 * tq + i) * 68 + 4 * dq] = o;
            }
        } else if (wv == 2) {
            float acc[4][4];
#pragma unroll
            for (int i = 0; i < 4; i++)
#pragma unroll
                for (int j = 0; j < 4; j++) acc[i][j] = 0.f;
            gemm_lds(vcT, tq, wS + 8192, dq, acc);
            float4 bb = *(const float4*)&blv[4 * dq];
#pragma unroll
            for (int i = 0; i < 4; i++) {
                acc[i][0] += bb.x; acc[i][1] += bb.y;
                acc[i][2] += bb.z; acc[i][3] += bb.w;
                *(float4*)&vlR[(4 * tq + i) * 68 + 4 * dq] =
                    make_float4(acc[i][0], acc[i][1], acc[i][2], acc[i][3]);
            }
            if (it < 2) {                       // vcur_next dead after last iter
#pragma unroll
                for (int j = 0; j < 4; j++) {
                    float4 cv = make_float4(acc[0][j], acc[1][j], acc[2][j], acc[3][j]);
                    *(float4*)&vcT[(4 * dq + j) * 20 + 4 * tq] = cv;
                }
            }
        }
        __syncthreads();

        // ---------------- P2: logits + softmax + P@vl (all waves) ----------
        float lg = 0.f;
#pragma unroll
        for (int c = 0; c < 16; ++c) {
            float4 a4 = *(float4*)&qsR[t2 * 68 + 4 * c];
            float4 b4 = *(float4*)&ksR[u  * 68 + 4 * c];
            lg = dot4acc(a4, b4, lg);
        }
        lg *= 0.125f;                        // 1/sqrt(64)
        float mx = lg;
        for (int off = 8; off; off >>= 1) mx = fmaxf(mx, __shfl_xor(mx, off));
        float e = __expf(lg - mx);
        float sm = e;
        for (int off = 8; off; off >>= 1) sm += __shfl_xor(sm, off);
        float p = e / sm;

        float4 ai = f4zero();
        int gbase = lane & 48;
#pragma unroll
        for (int tk = 0; tk < 16; ++tk) {
            float pk = __shfl(p, gbase + tk);
            ai = f4fma(pk, *(float4*)&vlR[tk * 68 + 4 * u], ai);
        }

        if (it == 0) {
            ai0 = ai;
        } else if (it == 1) {
            dlocal = fabsf(ai.x - ai0.x) + fabsf(ai.y - ai0.y) +
                     fabsf(ai.z - ai0.z) + fabsf(ai.w - ai0.w);
            *(float4*)&ai1g[rowi2 * 1024 + col2] = ai;
        } else {
            *(float4*)&ai2g[rowi2 * 1024 + col2] = ai;
        }
        if (it < 2) {                        // qcur += ai (register; 4 LDS writes)
            qreg = f4add(qreg, ai);
            qcT[(4 * u + 0) * 20 + t2] = qreg.x;
            qcT[(4 * u + 1) * 20 + t2] = qreg.y;
            qcT[(4 * u + 2) * 20 + t2] = qreg.z;
            qcT[(4 * u + 3) * 20 + t2] = qreg.w;
        }
        __syncthreads();
    }

    float ds = dlocal;
    for (int off = 32; off; off >>= 1) ds += __shfl_xor(ds, off);
    if (lane == 0) dred[wv] = ds;
    __syncthreads();
    if (tid == 0) atomicAdd(diffg, dred[0] + dred[1] + dred[2] + dred[3]);
}

// ---------------- K4: ai_sel @ Wo^T, split-K, atomic-add into out ------------
// out already holds bo everywhere (written by k_iter's broadcast blocks);
// each of the 8 K-slices atomic-adds its partial directly -- no wop buffer,
// no k_bo kernel. 8 f32 atomics/thread over 64K addresses, L2-resident.
__global__ __launch_bounds__(256) void k_wo(const float* __restrict__ ai1g,
                                            const float* __restrict__ ai2g,
                                            const float* __restrict__ diffg,
                                            const float* __restrict__ thrp,
                                            const float* __restrict__ facp,
                                            const float* __restrict__ Wo,
                                            float* __restrict__ out) {
    float diff = diffg[0] * (1.0f / 8388608.0f);
    const float* A = (diff < thrp[0] + facp[0] * diff) ? ai1g : ai2g;
    int jt  = blockIdx.x;
    int ksl = blockIdx.y;
    int k0  = ksl * 128;
    __shared__ float At[64][132];
    __shared__ float Bt[32][132];
    int tid = threadIdx.x;
    for (int i = tid; i < 2048; i += 256) {
        int r = i >> 5, kk = (i & 31) << 2;
        *(float4*)&At[r][kk] = *(const float4*)&A[r * 1024 + k0 + kk];
    }
    for (int i = tid; i < 1024; i += 256) {
        int r = i >> 5, kk = (i & 31) << 2;
        *(float4*)&Bt[r][kk] = *(const float4*)&Wo[(size_t)(jt * 32 + r) * 1024 + k0 + kk];
    }
    __syncthreads();
    int rg = tid >> 4, cg = tid & 15;
    float acc[4][2];
#pragma unroll
    for (int i = 0; i < 4; i++) { acc[i][0] = 0.f; acc[i][1] = 0.f; }
    for (int k = 0; k < 128; k += 4) {
        float4 b0 = *(float4*)&Bt[cg * 2 + 0][k];
        float4 b1 = *(float4*)&Bt[cg * 2 + 1][k];
#pragma unroll
        for (int i = 0; i < 4; i++) {
            float4 a = *(float4*)&At[rg * 4 + i][k];
            acc[i][0] = dot4acc(a, b0, acc[i][0]);
            acc[i][1] = dot4acc(a, b1, acc[i][1]);
        }
    }
    int colg = jt * 32 + cg * 2;
#pragma unroll
    for (int i = 0; i < 4; i++) {
        int ri = rg * 4 + i;                 // 0..63 = b*16 + t
        size_t orow = (size_t)((ri >> 4) * 2048 + (ri & 15)) * 1024;
        atomicAdd(&out[orow + colg + 0], acc[i][0]);
        atomicAdd(&out[orow + colg + 1], acc[i][1]);
    }
}

extern "C" void kernel_launch(void* const* d_in, const int* in_sizes, int n_in,
                              void* d_out, int out_size, void* d_ws, size_t ws_size,
                              hipStream_t stream) {
    (void)in_sizes; (void)n_in; (void)out_size; (void)ws_size;
    const float* x    = (const float*)d_in[0];
    const float* Wq   = (const float*)d_in[1];
    const float* bq   = (const float*)d_in[2];
    const float* Wk   = (const float*)d_in[3];
    const float* Wv   = (const float*)d_in[4];
    const float* bv   = (const float*)d_in[5];
    const float* Wo   = (const float*)d_in[6];
    const float* bo   = (const float*)d_in[7];
    const float* lna  = (const float*)d_in[8];
    const float* lnc  = (const float*)d_in[9];
    const float* lnd  = (const float*)d_in[10];
    const float* Wlq  = (const float*)d_in[11];
    const float* blq  = (const float*)d_in[12];
    const float* Wlk  = (const float*)d_in[13];
    const float* blk_ = (const float*)d_in[14];
    const float* Wlv  = (const float*)d_in[15];
    const float* blv  = (const float*)d_in[16];
    const float* temp = (const float*)d_in[17];
    const float* thr  = (const float*)d_in[18];
    const float* fac  = (const float*)d_in[19];
    float* ws  = (float*)d_ws;
    float* out = (float*)d_out;

    k_ln  <<<67, 256, 0, stream>>>(x, lna, Wlq, Wlk, Wlv,
                                   ws + WS_XN, ws + WS_WT, ws + WS_DIFF);
    k_qkv <<<dim3(96, 8), 256, 0, stream>>>(ws + WS_XN, Wq, Wk, Wv, ws + WS_QKVP);
    k_iter<<<64 + 8192, 256, 0, stream>>>(ws + WS_QKVP, ws + WS_WT, bq, bv,
                                          lnc, lnd, blq, blk_, blv, temp,
                                          bo, out,
                                          ws + WS_AI1, ws + WS_AI2, ws + WS_DIFF);
    k_wo  <<<dim3(32, 8), 256, 0, stream>>>(ws + WS_AI1, ws + WS_AI2, ws + WS_DIFF,
                                            thr, fac, Wo, out);
}